// Round 9
// baseline (388.631 us; speedup 1.0000x reference)
//
#include <hip/hip_runtime.h>

#define H 128
#define AP 136           // LDS row pitch in shorts (A tile)
#define OP 144           // LDS row pitch in bytes (fp8 out tile, 16B aligned)
#define BSH 8            // log2(nodes per bucket)
#define BSZ 256          // nodes per bucket
#define MAXB 512         // max buckets -> N <= 131072
#define NBLK 256         // scatter blocks (histogram row length)

typedef __attribute__((ext_vector_type(8))) short short8;
typedef __attribute__((ext_vector_type(4))) float floatx4;
typedef __attribute__((ext_vector_type(2))) float f32x2;

__device__ inline unsigned short f2b(float f) {   // fp32 -> bf16 RNE
  union { float f; unsigned u; } v; v.f = f;
  unsigned r = v.u + 0x7fffu + ((v.u >> 16) & 1u);
  return (unsigned short)(r >> 16);
}
__device__ inline float blo(unsigned u) { return __uint_as_float(u << 16); }
__device__ inline float bhi(unsigned u) { return __uint_as_float(u & 0xffff0000u); }
__device__ inline unsigned char f2f8(float f) {   // fp32 -> fp8 e4m3 (OCP, RNE)
  return (unsigned char)(__builtin_amdgcn_cvt_pk_fp8_f32(f, f, 0, false) & 0xff);
}
__device__ inline f32x2 fp8x2(unsigned u) {       // 2x fp8 (bits 0..15) -> 2x f32
#if __has_builtin(__builtin_amdgcn_cvt_pk_f32_fp8)
  return __builtin_amdgcn_cvt_pk_f32_fp8(u, false);
#else
  f32x2 r;
  r.x = __builtin_amdgcn_cvt_f32_fp8(u, 0);
  r.y = __builtin_amdgcn_cvt_f32_fp8(u, 1);
  return r;
#endif
}
__device__ inline float rfl_f(float x) {          // readfirstlane for float
  union { float f; int i; } u; u.f = x;
  u.i = __builtin_amdgcn_readfirstlane(u.i);
  return u.f;
}

// ============ CSR build: bucket-partitioned, LDS atomics only ============

// Pass A1 (+prep fused): blocks [0,NBLK) per-chunk bucket histogram;
// blocks NBLK..NBLK+1 transpose W1/W2 -> bf16; remaining blocks cvt x -> bf16.
__global__ __launch_bounds__(256) void k_bh_prep(const int* __restrict__ dst,
                                                 int* __restrict__ bhist,
                                                 int E, int NB, int chunk,
                                                 const float* __restrict__ W1,
                                                 const float* __restrict__ W2,
                                                 unsigned short* __restrict__ Wt1,
                                                 unsigned short* __restrict__ Wt2,
                                                 const float* __restrict__ x,
                                                 unsigned int* __restrict__ xb,
                                                 int xtotal) {
  int tid = threadIdx.x;
  int bx = blockIdx.x;
  if (bx < NBLK) {
    __shared__ int hst[MAXB];
    for (int b = tid; b < NB; b += 256) hst[b] = 0;
    __syncthreads();
    int s = bx * chunk;
    int eend = min(s + chunk, E);
    for (int e = s + tid; e < eend; e += 256)
      atomicAdd(&hst[dst[e] >> BSH], 1);
    __syncthreads();
    for (int b = tid; b < NB; b += 256) bhist[b * NBLK + bx] = hst[b];
  } else if (bx < NBLK + 2) {
    const float* W = (bx - NBLK) ? W2 : W1;
    unsigned short* Wt = (bx - NBLK) ? Wt2 : Wt1;
#pragma unroll
    for (int i = 0; i < 64; i++) {
      int idx = tid + 256 * i;
      int k = idx >> 7, n = idx & 127;
      Wt[n * 128 + k] = f2b(W[idx]);
    }
  } else {
    int i0 = (bx - NBLK - 2) * 2048 + tid * 8;   // 8 bf16x2 words / thread
    if (i0 + 8 <= xtotal) {
      const float4* x4 = (const float4*)x;       // float4 = 2 words
      unsigned w[8];
#pragma unroll
      for (int j = 0; j < 4; j++) {
        float4 v = x4[i0 / 2 + j];
        w[2 * j]     = (unsigned)f2b(v.x) | ((unsigned)f2b(v.y) << 16);
        w[2 * j + 1] = (unsigned)f2b(v.z) | ((unsigned)f2b(v.w) << 16);
      }
      *(uint4*)(xb + i0)     = make_uint4(w[0], w[1], w[2], w[3]);
      *(uint4*)(xb + i0 + 4) = make_uint4(w[4], w[5], w[6], w[7]);
    } else {
      for (int i = i0; i < xtotal; i++) {
        float2 v = ((const float2*)x)[i];
        xb[i] = (unsigned)f2b(v.x) | ((unsigned)f2b(v.y) << 16);
      }
    }
  }
}

// Pass A2: exclusive scan of [bucket][block] histogram. 1024 threads, each owns
// 128 ints register-resident (32x int4, all loads in flight), LDS scan of sums.
__global__ __launch_bounds__(1024) void k_bscan(const int* __restrict__ bhist,
                                                int* __restrict__ boff2, int total) {
  __shared__ int ps[1024];
  int tid = threadIdx.x;
  int base = tid * 128;
  int4 v[32];
  int sum = 0;
  if (base < total) {
    const int4* row = (const int4*)(bhist + base);
#pragma unroll
    for (int j = 0; j < 32; j++) v[j] = row[j];
#pragma unroll
    for (int j = 0; j < 32; j++) sum += v[j].x + v[j].y + v[j].z + v[j].w;
  }
  ps[tid] = sum;
  __syncthreads();
  for (int off = 1; off < 1024; off <<= 1) {
    int t = (tid >= off) ? ps[tid - off] : 0;
    __syncthreads();
    ps[tid] += t;
    __syncthreads();
  }
  int run = ps[tid] - sum;          // exclusive base for this thread's range
  if (base < total) {
    int4* orow = (int4*)(boff2 + base);
#pragma unroll
    for (int j = 0; j < 32; j++) {
      int4 o;
      o.x = run; run += v[j].x;
      o.y = run; run += v[j].y;
      o.z = run; run += v[j].z;
      o.w = run; run += v[j].w;
      orow[j] = o;
    }
  }
}

// Pass A3: scatter edges into bucket-contiguous storage, packed (src<<BSH)|local_dst.
__global__ __launch_bounds__(256) void k_bscatter(const int* __restrict__ src,
                                                  const int* __restrict__ dst,
                                                  const int* __restrict__ boff2,
                                                  int* __restrict__ bed,
                                                  int E, int NB, int chunk) {
  __shared__ int pos[MAXB];
  int tid = threadIdx.x;
  for (int b = tid; b < NB; b += 256) pos[b] = boff2[b * NBLK + blockIdx.x];
  __syncthreads();
  int s = blockIdx.x * chunk;
  int eend = min(s + chunk, E);
  for (int e = s + tid; e < eend; e += 256) {
    int d = dst[e];
    int p = atomicAdd(&pos[d >> BSH], 1);
    bed[p] = (src[e] << BSH) | (d & (BSZ - 1));
  }
}

// Pass B: one block per bucket (256 nodes). LDS count -> LDS scan (roff =
// bucket base + local exclusive scan) -> LDS-atomic rank scatter to csr.
// Also produces dinv. 391 blocks @ N=100000 (was 196x512: 0.4 blocks/CU).
__global__ __launch_bounds__(256) void k_build(const int* __restrict__ bed,
                                               const int* __restrict__ boff2,
                                               int* __restrict__ roff,
                                               float* __restrict__ dinv,
                                               int* __restrict__ csr,
                                               int N, int E, int NB) {
  __shared__ int cnt[BSZ];
  __shared__ int pos[BSZ];
  __shared__ int ps[BSZ];
  int b = blockIdx.x, tid = threadIdx.x;
  int bs = boff2[b * NBLK];
  int be = (b + 1 < NB) ? boff2[(b + 1) * NBLK] : E;
  int n0 = b << BSH;
  cnt[tid] = 0;
  __syncthreads();
  for (int e = bs + tid; e < be; e += 256)
    atomicAdd(&cnt[bed[e] & (BSZ - 1)], 1);
  __syncthreads();
  int c = cnt[tid];
  ps[tid] = c;
  __syncthreads();
  for (int off = 1; off < 256; off <<= 1) {
    int t = (tid >= off) ? ps[tid - off] : 0;
    __syncthreads();
    ps[tid] += t;
    __syncthreads();
  }
  int base = bs + ps[tid] - c;      // exclusive
  pos[tid] = base;
  int node = n0 + tid;
  if (node < N) {
    roff[node] = base;
    dinv[node] = rsqrtf((float)c + 1.0f);
  }
  __syncthreads();
  for (int e = bs + tid; e < be; e += 256) {
    int v = bed[e];
    int p = atomicAdd(&pos[v & (BSZ - 1)], 1);
    csr[p] = v >> BSH;
  }
  if (b == 0 && tid == 0) roff[N] = E;
}

// ---------------- bf16 MFMA GEMM: out_fp8 = in_bf16 @ W ----------------
// B fragments from global (Wt 32KB, L2-resident); LDS-staged coalesced output.
// Blocks >= gb (first call only) build cfa[e] = dinv[csr[e]] (layer-invariant).
__global__ __launch_bounds__(256) void k_gemm(const unsigned int* __restrict__ in, // bf16x2 [n][64]
                                              const unsigned short* __restrict__ Wt, // [n][k] bf16
                                              unsigned char* __restrict__ out,       // [m][n] fp8
                                              int n, int gb,
                                              const int* __restrict__ csr,
                                              const float* __restrict__ dinv,
                                              float* __restrict__ cfa, int Ecf) {
  if (blockIdx.x >= gb) {
    int i0 = (blockIdx.x - gb) * 2048 + threadIdx.x * 8;
    if (i0 + 8 <= Ecf) {
      int4 c0 = *(const int4*)(csr + i0);
      int4 c1 = *(const int4*)(csr + i0 + 4);
      float4 f0, f1;
      f0.x = dinv[c0.x]; f0.y = dinv[c0.y]; f0.z = dinv[c0.z]; f0.w = dinv[c0.w];
      f1.x = dinv[c1.x]; f1.y = dinv[c1.y]; f1.z = dinv[c1.z]; f1.w = dinv[c1.w];
      *(float4*)(cfa + i0) = f0;
      *(float4*)(cfa + i0 + 4) = f1;
    } else {
      for (int i = i0; i < Ecf; i++) cfa[i] = dinv[csr[i]];
    }
    return;
  }
  __shared__ short As[64 * AP];     // 17408 B; reused as fp8 out tile (64*OP=9216 B)
  int tid = threadIdx.x;
  int wave = tid >> 6, lane = tid & 63;
  int quad = lane >> 4, l16 = lane & 15;
  int row0 = blockIdx.x * 64;

  // B fragments: global -> regs (issued first; overlap A staging below)
  short8 b[4][2];
#pragma unroll
  for (int ks = 0; ks < 4; ks++)
#pragma unroll
    for (int nt = 0; nt < 2; nt++)
      b[ks][nt] = *(const short8*)&Wt[(wave * 32 + nt * 16 + l16) * 128 + ks * 32 + quad * 8];

  // stage A: 64 rows x 128 shorts = 1024 16B-chunks
  const float4* in4 = (const float4*)in;
#pragma unroll
  for (int i = 0; i < 4; i++) {
    int idx = tid + 256 * i;
    int r = idx >> 4, c = idx & 15;
    int gr = row0 + r;
    float4 v = make_float4(0.f, 0.f, 0.f, 0.f);
    if (gr < n) v = in4[(size_t)gr * 16 + c];
    *(float4*)&As[r * AP + c * 8] = v;
  }
  __syncthreads();

  floatx4 acc[4][2];
#pragma unroll
  for (int mt = 0; mt < 4; mt++)
#pragma unroll
    for (int nt = 0; nt < 2; nt++) acc[mt][nt] = (floatx4)(0.f);

#pragma unroll
  for (int ks = 0; ks < 4; ks++) {
    short8 a[4];
#pragma unroll
    for (int mt = 0; mt < 4; mt++)
      a[mt] = *(const short8*)&As[(mt * 16 + l16) * AP + ks * 32 + quad * 8];
#pragma unroll
    for (int mt = 0; mt < 4; mt++)
#pragma unroll
      for (int nt = 0; nt < 2; nt++)
        acc[mt][nt] = __builtin_amdgcn_mfma_f32_16x16x32_bf16(a[mt], b[ks][nt], acc[mt][nt], 0, 0, 0);
  }

  // epilogue: fp8 tile -> LDS, then coalesced dwordx4 global stores
  __syncthreads();                  // all As reads done; safe to reuse
  unsigned char* ob = (unsigned char*)As;
#pragma unroll
  for (int mt = 0; mt < 4; mt++)
#pragma unroll
    for (int nt = 0; nt < 2; nt++)
#pragma unroll
      for (int r = 0; r < 4; r++)
        ob[(mt * 16 + quad * 4 + r) * OP + wave * 32 + nt * 16 + l16] =
            f2f8(acc[mt][nt][r]);
  __syncthreads();
  int orow = tid >> 2, ochunk = tid & 3;     // 4 threads cover one 128B row
  int gr2 = row0 + orow;
  if (gr2 < n) {
    uint4 v0 = *(const uint4*)&ob[orow * OP + ochunk * 32];
    uint4 v1 = *(const uint4*)&ob[orow * OP + ochunk * 32 + 16];
    *(uint4*)&out[(size_t)gr2 * H + ochunk * 32] = v0;
    *(uint4*)&out[(size_t)gr2 * H + ochunk * 32 + 16] = v1;
  }
}

// ---------------- aggregation: one wave per node, fp8 h gathers (128B rows) ----
// y[i,:] = b + xb[i,:] + dinv[i]*(dinv[i]*h[i,:] + sum_e cfa[e]*h[src,:])
// Round-5 burst structure (measured best) + di factored out of the per-edge FMA.
__global__ __launch_bounds__(256) void k_agg(const unsigned short* __restrict__ h, // fp8 pairs
                                             const int* __restrict__ csr,
                                             const int* __restrict__ roff,
                                             const float* __restrict__ dinv,
                                             const float* __restrict__ cfa,
                                             const float* __restrict__ bias,
                                             const unsigned int* __restrict__ xb,
                                             float* __restrict__ out32,
                                             unsigned int* __restrict__ out16,
                                             int n, int write16) {
  int wave = threadIdx.x >> 6;
  int lane = threadIdx.x & 63;
  int node = blockIdx.x * 4 + wave;
  if (node >= n) return;

  float di = dinv[node];
  unsigned su = h[(size_t)node * 64 + lane];
  unsigned xu = xb[(size_t)node * 64 + lane];
  float2 bv = ((const float2*)bias)[lane];
  f32x2 sp = fp8x2(su);
  float ea0 = 0.f, ea1 = 0.f;       // edge sums (di factored out)

  int e0 = roff[node], e1 = roff[node + 1];
  int e = e0;
  for (; e + 16 <= e1; e += 16) {
    int eu = __builtin_amdgcn_readfirstlane(e);
    float cf[16];
#pragma unroll
    for (int k = 0; k < 16; k++) cf[k] = rfl_f(cfa[eu + k]);
    int idx[16];
#pragma unroll
    for (int k = 0; k < 16; k++) idx[k] = __builtin_amdgcn_readfirstlane(csr[eu + k]);
    unsigned u[16];
#pragma unroll
    for (int k = 0; k < 16; k++) u[k] = (h + ((size_t)idx[k] << 6))[lane];
#pragma unroll
    for (int k = 0; k < 16; k++) {
      f32x2 p = fp8x2(u[k]);
      ea0 += cf[k] * p.x;
      ea1 += cf[k] * p.y;
    }
  }
  for (; e + 4 <= e1; e += 4) {
    int eu = __builtin_amdgcn_readfirstlane(e);
    float cf[4];
#pragma unroll
    for (int k = 0; k < 4; k++) cf[k] = rfl_f(cfa[eu + k]);
    int idx[4];
#pragma unroll
    for (int k = 0; k < 4; k++) idx[k] = __builtin_amdgcn_readfirstlane(csr[eu + k]);
    unsigned u[4];
#pragma unroll
    for (int k = 0; k < 4; k++) u[k] = (h + ((size_t)idx[k] << 6))[lane];
#pragma unroll
    for (int k = 0; k < 4; k++) {
      f32x2 p = fp8x2(u[k]);
      ea0 += cf[k] * p.x;
      ea1 += cf[k] * p.y;
    }
  }
  for (; e < e1; e++) {
    int eu = __builtin_amdgcn_readfirstlane(e);
    float cf = rfl_f(cfa[eu]);
    int s = __builtin_amdgcn_readfirstlane(csr[eu]);
    unsigned u = h[(size_t)s * 64 + lane];
    f32x2 p = fp8x2(u);
    ea0 += cf * p.x;
    ea1 += cf * p.y;
  }
  float acc0 = bv.x + blo(xu) + di * (di * sp.x + ea0);
  float acc1 = bv.y + bhi(xu) + di * (di * sp.y + ea1);
  if (write16) {
    out16[(size_t)node * 64 + lane] =
        (unsigned)f2b(fmaxf(acc0, 0.f)) | ((unsigned)f2b(fmaxf(acc1, 0.f)) << 16);
  } else {
    ((float2*)out32)[(size_t)node * 64 + lane] = make_float2(acc0, acc1);
  }
}

extern "C" void kernel_launch(void* const* d_in, const int* in_sizes, int n_in,
                              void* d_out, int out_size, void* d_ws, size_t ws_size,
                              hipStream_t stream) {
  const float* x = (const float*)d_in[0];
  const int* src = (const int*)d_in[1];
  const int* dst = (const int*)d_in[2];
  const float* W1 = (const float*)d_in[3];
  const float* b1 = (const float*)d_in[4];
  const float* W2 = (const float*)d_in[5];
  const float* b2 = (const float*)d_in[6];
  int N = in_sizes[0] / H;
  int E = in_sizes[1];
  float* out = (float*)d_out;

  char* p = (char*)d_ws;
  auto alloc = [&](size_t bytes) {
    char* q = p;
    p += (bytes + 255) & ~(size_t)255;
    return q;
  };
  int* roff = (int*)alloc((size_t)(N + 1) * 4);
  float* dinv = (float*)alloc((size_t)N * 4);
  int* csr = (int*)alloc((size_t)E * 4);
  float* cfa = (float*)alloc((size_t)E * 4);                          // dinv[csr[e]]
  unsigned int* xb = (unsigned int*)alloc((size_t)N * H * 2);         // bf16 x
  unsigned char* htmp = (unsigned char*)alloc((size_t)N * H);         // fp8 h = f@W
  unsigned int* fbuf = (unsigned int*)alloc((size_t)N * H * 2);       // bf16 relu(y)
  unsigned short* Wt1 = (unsigned short*)alloc(128 * 128 * 2);
  unsigned short* Wt2 = (unsigned short*)alloc(128 * 128 * 2);
  int* bhist = (int*)alloc((size_t)MAXB * NBLK * 4);
  int* boff2 = (int*)alloc((size_t)MAXB * NBLK * 4);
  int* bed = (int*)alloc((size_t)E * 4);     // bucketed packed edges

  int NB = (N + BSZ - 1) >> BSH;             // 391 for N=100000 (requires NB<=512)
  int chunk = (E + NBLK - 1) / NBLK;         // 6250

  int xtotal = N * (H / 2);
  int xblocks = (xtotal + 2047) / 2048;      // 8 words / thread

  // CSR build (no global atomics, no memset) + prep fused into pass A1
  k_bh_prep<<<NBLK + 2 + xblocks, 256, 0, stream>>>(dst, bhist, E, NB, chunk,
                                                    W1, W2, Wt1, Wt2, x, xb, xtotal);
  k_bscan<<<1, 1024, 0, stream>>>(bhist, boff2, NB * NBLK);
  k_bscatter<<<NBLK, 256, 0, stream>>>(src, dst, boff2, bed, E, NB, chunk);
  k_build<<<NB, 256, 0, stream>>>(bed, boff2, roff, dinv, csr, N, E, NB);

  int gb = (N + 63) / 64;
  int ab = (N + 3) / 4;
  int cfblocks = (E + 2047) / 2048;

  // layer 1: h = xb @ W1 (+ cfa build in extra blocks); y1 = agg + b1 + xb; relu
  k_gemm<<<gb + cfblocks, 256, 0, stream>>>(xb, Wt1, htmp, N, gb, csr, dinv, cfa, E);
  k_agg<<<ab, 256, 0, stream>>>((const unsigned short*)htmp, csr, roff, dinv, cfa, b1,
                                xb, nullptr, fbuf, N, 1);
  // layer 2
  k_gemm<<<gb, 256, 0, stream>>>(fbuf, Wt2, htmp, N, gb, nullptr, nullptr, nullptr, 0);
  k_agg<<<ab, 256, 0, stream>>>((const unsigned short*)htmp, csr, roff, dinv, cfa, b2,
                                xb, nullptr, fbuf, N, 1);
  // layer 3 -> fp32 out
  k_gemm<<<gb, 256, 0, stream>>>(fbuf, Wt2, htmp, N, gb, nullptr, nullptr, nullptr, 0);
  k_agg<<<ab, 256, 0, stream>>>((const unsigned short*)htmp, csr, roff, dinv, cfa, b2,
                                xb, out, nullptr, N, 0);
}

// Round 10
// 367.832 us; speedup vs baseline: 1.0565x; 1.0565x over previous
//
#include <hip/hip_runtime.h>

#define H 128
#define AP 136           // LDS row pitch in shorts
#define BSH 9            // log2(nodes per bucket)
#define BSZ 512          // nodes per bucket
#define MAXB 256         // max buckets -> N <= 131072
#define NBLK 256         // scatter blocks (histogram row length)

typedef __attribute__((ext_vector_type(8))) short short8;
typedef __attribute__((ext_vector_type(4))) float floatx4;
typedef __attribute__((ext_vector_type(2))) float f32x2;

__device__ inline unsigned short f2b(float f) {   // fp32 -> bf16 RNE
  union { float f; unsigned u; } v; v.f = f;
  unsigned r = v.u + 0x7fffu + ((v.u >> 16) & 1u);
  return (unsigned short)(r >> 16);
}
__device__ inline float blo(unsigned u) { return __uint_as_float(u << 16); }
__device__ inline float bhi(unsigned u) { return __uint_as_float(u & 0xffff0000u); }
__device__ inline unsigned char f2f8(float f) {   // fp32 -> fp8 e4m3 (OCP, RNE)
  return (unsigned char)(__builtin_amdgcn_cvt_pk_fp8_f32(f, f, 0, false) & 0xff);
}
__device__ inline f32x2 fp8x2(unsigned u) {       // 2x fp8 (bits 0..15) -> 2x f32
#if __has_builtin(__builtin_amdgcn_cvt_pk_f32_fp8)
  return __builtin_amdgcn_cvt_pk_f32_fp8(u, false);
#else
  f32x2 r;
  r.x = __builtin_amdgcn_cvt_f32_fp8(u, 0);
  r.y = __builtin_amdgcn_cvt_f32_fp8(u, 1);
  return r;
#endif
}
__device__ inline float rfl_f(float x) {          // readfirstlane for float
  union { float f; int i; } u; u.f = x;
  u.i = __builtin_amdgcn_readfirstlane(u.i);
  return u.f;
}

// ============ CSR build: bucket-partitioned, LDS atomics only ============

// Pass A1 (+prep fused): blocks [0,NBLK) per-chunk bucket histogram;
// blocks NBLK..NBLK+1 transpose W1/W2 -> bf16; remaining blocks cvt x -> bf16.
__global__ __launch_bounds__(256) void k_bh_prep(const int* __restrict__ dst,
                                                 int* __restrict__ bhist,
                                                 int E, int NB, int chunk,
                                                 const float* __restrict__ W1,
                                                 const float* __restrict__ W2,
                                                 unsigned short* __restrict__ Wt1,
                                                 unsigned short* __restrict__ Wt2,
                                                 const float* __restrict__ x,
                                                 unsigned int* __restrict__ xb,
                                                 int xtotal) {
  int tid = threadIdx.x;
  int bx = blockIdx.x;
  if (bx < NBLK) {
    __shared__ int hst[MAXB];
    hst[tid] = 0;
    __syncthreads();
    int s = bx * chunk;
    int eend = min(s + chunk, E);
    for (int e = s + tid; e < eend; e += 256)
      atomicAdd(&hst[dst[e] >> BSH], 1);
    __syncthreads();
    if (tid < NB) bhist[tid * NBLK + bx] = hst[tid];
  } else if (bx < NBLK + 2) {
    const float* W = (bx - NBLK) ? W2 : W1;
    unsigned short* Wt = (bx - NBLK) ? Wt2 : Wt1;
#pragma unroll
    for (int i = 0; i < 64; i++) {
      int idx = tid + 256 * i;
      int k = idx >> 7, n = idx & 127;
      Wt[n * 128 + k] = f2b(W[idx]);
    }
  } else {
    int i0 = (bx - NBLK - 2) * 2048 + tid * 8;   // 8 bf16x2 words / thread
    if (i0 + 8 <= xtotal) {
      const float4* x4 = (const float4*)x;       // float4 = 2 words
      unsigned w[8];
#pragma unroll
      for (int j = 0; j < 4; j++) {
        float4 v = x4[i0 / 2 + j];
        w[2 * j]     = (unsigned)f2b(v.x) | ((unsigned)f2b(v.y) << 16);
        w[2 * j + 1] = (unsigned)f2b(v.z) | ((unsigned)f2b(v.w) << 16);
      }
      *(uint4*)(xb + i0)     = make_uint4(w[0], w[1], w[2], w[3]);
      *(uint4*)(xb + i0 + 4) = make_uint4(w[4], w[5], w[6], w[7]);
    } else {
      for (int i = i0; i < xtotal; i++) {
        float2 v = ((const float2*)x)[i];
        xb[i] = (unsigned)f2b(v.x) | ((unsigned)f2b(v.y) << 16);
      }
    }
  }
}

// Pass A2: exclusive scan of [bucket][block] histogram. 512 threads, each owns
// 128 ints register-resident (32x int4, all loads in flight), LDS scan of sums.
__global__ __launch_bounds__(512) void k_bscan(const int* __restrict__ bhist,
                                               int* __restrict__ boff2, int total) {
  __shared__ int ps[512];
  int tid = threadIdx.x;
  int base = tid * 128;
  int4 v[32];
  int sum = 0;
  if (base < total) {
    const int4* row = (const int4*)(bhist + base);
#pragma unroll
    for (int j = 0; j < 32; j++) v[j] = row[j];
#pragma unroll
    for (int j = 0; j < 32; j++) sum += v[j].x + v[j].y + v[j].z + v[j].w;
  }
  ps[tid] = sum;
  __syncthreads();
  for (int off = 1; off < 512; off <<= 1) {
    int t = (tid >= off) ? ps[tid - off] : 0;
    __syncthreads();
    ps[tid] += t;
    __syncthreads();
  }
  int run = ps[tid] - sum;          // exclusive base for this thread's range
  if (base < total) {
    int4* orow = (int4*)(boff2 + base);
#pragma unroll
    for (int j = 0; j < 32; j++) {
      int4 o;
      o.x = run; run += v[j].x;
      o.y = run; run += v[j].y;
      o.z = run; run += v[j].z;
      o.w = run; run += v[j].w;
      orow[j] = o;
    }
  }
}

// Pass A3: scatter edges into bucket-contiguous storage, packed (src<<BSH)|local_dst.
__global__ __launch_bounds__(256) void k_bscatter(const int* __restrict__ src,
                                                  const int* __restrict__ dst,
                                                  const int* __restrict__ boff2,
                                                  int* __restrict__ bed,
                                                  int E, int NB, int chunk) {
  __shared__ int pos[MAXB];
  int tid = threadIdx.x;
  if (tid < NB) pos[tid] = boff2[tid * NBLK + blockIdx.x];
  __syncthreads();
  int s = blockIdx.x * chunk;
  int eend = min(s + chunk, E);
  for (int e = s + tid; e < eend; e += 256) {
    int d = dst[e];
    int p = atomicAdd(&pos[d >> BSH], 1);
    bed[p] = (src[e] << BSH) | (d & (BSZ - 1));
  }
}

// Pass B: one block per bucket. LDS count -> LDS scan (roff = bucket base + local
// exclusive scan) -> LDS-atomic rank scatter to csr. Also produces dinv.
__global__ __launch_bounds__(512) void k_build(const int* __restrict__ bed,
                                               const int* __restrict__ boff2,
                                               int* __restrict__ roff,
                                               float* __restrict__ dinv,
                                               int* __restrict__ csr,
                                               int N, int E, int NB) {
  __shared__ int cnt[BSZ];
  __shared__ int pos[BSZ];
  __shared__ int ps[BSZ];
  int b = blockIdx.x, tid = threadIdx.x;
  int bs = boff2[b * NBLK];
  int be = (b + 1 < NB) ? boff2[(b + 1) * NBLK] : E;
  int n0 = b << BSH;
  cnt[tid] = 0;
  __syncthreads();
  for (int e = bs + tid; e < be; e += 512)
    atomicAdd(&cnt[bed[e] & (BSZ - 1)], 1);
  __syncthreads();
  int c = cnt[tid];
  ps[tid] = c;
  __syncthreads();
  for (int off = 1; off < 512; off <<= 1) {
    int t = (tid >= off) ? ps[tid - off] : 0;
    __syncthreads();
    ps[tid] += t;
    __syncthreads();
  }
  int base = bs + ps[tid] - c;      // exclusive
  pos[tid] = base;
  int node = n0 + tid;
  if (node < N) {
    roff[node] = base;
    dinv[node] = rsqrtf((float)c + 1.0f);
  }
  __syncthreads();
  for (int e = bs + tid; e < be; e += 512) {
    int v = bed[e];
    int p = atomicAdd(&pos[v & (BSZ - 1)], 1);
    csr[p] = v >> BSH;
  }
  if (b == 0 && tid == 0) roff[N] = E;
}

// ---------------- bf16 MFMA GEMM: out_fp8 = in_bf16 @ W ----------------
// Round-5 form (measured best total): A+B staged in LDS, simple byte-store
// epilogue. Blocks >= gb (first call only) build cfa[e] = dinv[csr[e]].
__global__ __launch_bounds__(256) void k_gemm(const unsigned int* __restrict__ in, // bf16x2 [n][64]
                                              const unsigned short* __restrict__ Wt, // [n][k] bf16
                                              unsigned char* __restrict__ out,       // [m][n] fp8
                                              int n, int gb,
                                              const int* __restrict__ csr,
                                              const float* __restrict__ dinv,
                                              float* __restrict__ cfa, int Ecf) {
  if (blockIdx.x >= gb) {
    int i0 = (blockIdx.x - gb) * 2048 + threadIdx.x * 8;
    if (i0 + 8 <= Ecf) {
      int4 c0 = *(const int4*)(csr + i0);
      int4 c1 = *(const int4*)(csr + i0 + 4);
      float4 f0, f1;
      f0.x = dinv[c0.x]; f0.y = dinv[c0.y]; f0.z = dinv[c0.z]; f0.w = dinv[c0.w];
      f1.x = dinv[c1.x]; f1.y = dinv[c1.y]; f1.z = dinv[c1.z]; f1.w = dinv[c1.w];
      *(float4*)(cfa + i0) = f0;
      *(float4*)(cfa + i0 + 4) = f1;
    } else {
      for (int i = i0; i < Ecf; i++) cfa[i] = dinv[csr[i]];
    }
    return;
  }
  __shared__ short As[64 * AP];
  __shared__ short Bs[128 * AP];
  int tid = threadIdx.x;
  int wave = tid >> 6, lane = tid & 63;
  int quad = lane >> 4, l16 = lane & 15;
  int row0 = blockIdx.x * 64;

  const float4* in4 = (const float4*)in;
#pragma unroll
  for (int i = 0; i < 4; i++) {
    int idx = tid + 256 * i;
    int r = idx >> 4, c = idx & 15;
    int gr = row0 + r;
    float4 v = make_float4(0.f, 0.f, 0.f, 0.f);
    if (gr < n) v = in4[(size_t)gr * 16 + c];
    *(float4*)&As[r * AP + c * 8] = v;
  }
  const float4* Wt4 = (const float4*)Wt;
#pragma unroll
  for (int i = 0; i < 8; i++) {
    int idx = tid + 256 * i;
    int nr = idx >> 4, c = idx & 15;
    *(float4*)&Bs[nr * AP + c * 8] = Wt4[nr * 16 + c];
  }
  __syncthreads();

  floatx4 acc[4][2];
#pragma unroll
  for (int mt = 0; mt < 4; mt++)
#pragma unroll
    for (int nt = 0; nt < 2; nt++) acc[mt][nt] = (floatx4)(0.f);

#pragma unroll
  for (int ks = 0; ks < 4; ks++) {
    short8 a[4], b[2];
#pragma unroll
    for (int mt = 0; mt < 4; mt++)
      a[mt] = *(const short8*)&As[(mt * 16 + l16) * AP + ks * 32 + quad * 8];
#pragma unroll
    for (int nt = 0; nt < 2; nt++)
      b[nt] = *(const short8*)&Bs[(wave * 32 + nt * 16 + l16) * AP + ks * 32 + quad * 8];
#pragma unroll
    for (int mt = 0; mt < 4; mt++)
#pragma unroll
      for (int nt = 0; nt < 2; nt++)
        acc[mt][nt] = __builtin_amdgcn_mfma_f32_16x16x32_bf16(a[mt], b[nt], acc[mt][nt], 0, 0, 0);
  }

#pragma unroll
  for (int mt = 0; mt < 4; mt++) {
#pragma unroll
    for (int nt = 0; nt < 2; nt++) {
#pragma unroll
      for (int r = 0; r < 4; r++) {
        int gr = row0 + mt * 16 + quad * 4 + r;
        if (gr < n)
          out[(size_t)gr * H + wave * 32 + nt * 16 + l16] = f2f8(acc[mt][nt][r]);
      }
    }
  }
}

// ---------------- aggregation: one wave per node, fp8 h gathers (128B rows) ----
// y[i,:] = b + xb[i,:] + dinv[i]*(dinv[i]*h[i,:] + sum_e cfa[e]*h[src,:])
// Round-5 burst structure + di factored out of the per-edge FMA (round-9 win).
__global__ __launch_bounds__(256) void k_agg(const unsigned short* __restrict__ h, // fp8 pairs
                                             const int* __restrict__ csr,
                                             const int* __restrict__ roff,
                                             const float* __restrict__ dinv,
                                             const float* __restrict__ cfa,
                                             const float* __restrict__ bias,
                                             const unsigned int* __restrict__ xb,
                                             float* __restrict__ out32,
                                             unsigned int* __restrict__ out16,
                                             int n, int write16) {
  int wave = threadIdx.x >> 6;
  int lane = threadIdx.x & 63;
  int node = blockIdx.x * 4 + wave;
  if (node >= n) return;

  float di = dinv[node];
  unsigned su = h[(size_t)node * 64 + lane];
  unsigned xu = xb[(size_t)node * 64 + lane];
  float2 bv = ((const float2*)bias)[lane];
  f32x2 sp = fp8x2(su);
  float ea0 = 0.f, ea1 = 0.f;       // edge sums (di factored out)

  int e0 = roff[node], e1 = roff[node + 1];
  int e = e0;
  for (; e + 16 <= e1; e += 16) {
    int eu = __builtin_amdgcn_readfirstlane(e);
    float cf[16];
#pragma unroll
    for (int k = 0; k < 16; k++) cf[k] = rfl_f(cfa[eu + k]);
    int idx[16];
#pragma unroll
    for (int k = 0; k < 16; k++) idx[k] = __builtin_amdgcn_readfirstlane(csr[eu + k]);
    unsigned u[16];
#pragma unroll
    for (int k = 0; k < 16; k++) u[k] = (h + ((size_t)idx[k] << 6))[lane];
#pragma unroll
    for (int k = 0; k < 16; k++) {
      f32x2 p = fp8x2(u[k]);
      ea0 += cf[k] * p.x;
      ea1 += cf[k] * p.y;
    }
  }
  for (; e + 4 <= e1; e += 4) {
    int eu = __builtin_amdgcn_readfirstlane(e);
    float cf[4];
#pragma unroll
    for (int k = 0; k < 4; k++) cf[k] = rfl_f(cfa[eu + k]);
    int idx[4];
#pragma unroll
    for (int k = 0; k < 4; k++) idx[k] = __builtin_amdgcn_readfirstlane(csr[eu + k]);
    unsigned u[4];
#pragma unroll
    for (int k = 0; k < 4; k++) u[k] = (h + ((size_t)idx[k] << 6))[lane];
#pragma unroll
    for (int k = 0; k < 4; k++) {
      f32x2 p = fp8x2(u[k]);
      ea0 += cf[k] * p.x;
      ea1 += cf[k] * p.y;
    }
  }
  for (; e < e1; e++) {
    int eu = __builtin_amdgcn_readfirstlane(e);
    float cf = rfl_f(cfa[eu]);
    int s = __builtin_amdgcn_readfirstlane(csr[eu]);
    unsigned u = h[(size_t)s * 64 + lane];
    f32x2 p = fp8x2(u);
    ea0 += cf * p.x;
    ea1 += cf * p.y;
  }
  float acc0 = bv.x + blo(xu) + di * (di * sp.x + ea0);
  float acc1 = bv.y + bhi(xu) + di * (di * sp.y + ea1);
  if (write16) {
    out16[(size_t)node * 64 + lane] =
        (unsigned)f2b(fmaxf(acc0, 0.f)) | ((unsigned)f2b(fmaxf(acc1, 0.f)) << 16);
  } else {
    ((float2*)out32)[(size_t)node * 64 + lane] = make_float2(acc0, acc1);
  }
}

extern "C" void kernel_launch(void* const* d_in, const int* in_sizes, int n_in,
                              void* d_out, int out_size, void* d_ws, size_t ws_size,
                              hipStream_t stream) {
  const float* x = (const float*)d_in[0];
  const int* src = (const int*)d_in[1];
  const int* dst = (const int*)d_in[2];
  const float* W1 = (const float*)d_in[3];
  const float* b1 = (const float*)d_in[4];
  const float* W2 = (const float*)d_in[5];
  const float* b2 = (const float*)d_in[6];
  int N = in_sizes[0] / H;
  int E = in_sizes[1];
  float* out = (float*)d_out;

  char* p = (char*)d_ws;
  auto alloc = [&](size_t bytes) {
    char* q = p;
    p += (bytes + 255) & ~(size_t)255;
    return q;
  };
  int* roff = (int*)alloc((size_t)(N + 1) * 4);
  float* dinv = (float*)alloc((size_t)N * 4);
  int* csr = (int*)alloc((size_t)E * 4);
  float* cfa = (float*)alloc((size_t)E * 4);                          // dinv[csr[e]]
  unsigned int* xb = (unsigned int*)alloc((size_t)N * H * 2);         // bf16 x
  unsigned char* htmp = (unsigned char*)alloc((size_t)N * H);         // fp8 h = f@W
  unsigned int* fbuf = (unsigned int*)alloc((size_t)N * H * 2);       // bf16 relu(y)
  unsigned short* Wt1 = (unsigned short*)alloc(128 * 128 * 2);
  unsigned short* Wt2 = (unsigned short*)alloc(128 * 128 * 2);
  int* bhist = (int*)alloc((size_t)MAXB * NBLK * 4);
  int* boff2 = (int*)alloc((size_t)MAXB * NBLK * 4);
  int* bed = (int*)alloc((size_t)E * 4);     // bucketed packed edges

  int NB = (N + BSZ - 1) >> BSH;             // 196 for N=100000 (requires NB<=256)
  int chunk = (E + NBLK - 1) / NBLK;         // 6250

  int xtotal = N * (H / 2);
  int xblocks = (xtotal + 2047) / 2048;      // 8 words / thread

  // CSR build (no global atomics, no memset) + prep fused into pass A1
  k_bh_prep<<<NBLK + 2 + xblocks, 256, 0, stream>>>(dst, bhist, E, NB, chunk,
                                                    W1, W2, Wt1, Wt2, x, xb, xtotal);
  k_bscan<<<1, 512, 0, stream>>>(bhist, boff2, NB * NBLK);
  k_bscatter<<<NBLK, 256, 0, stream>>>(src, dst, boff2, bed, E, NB, chunk);
  k_build<<<NB, 512, 0, stream>>>(bed, boff2, roff, dinv, csr, N, E, NB);

  int gb = (N + 63) / 64;
  int ab = (N + 3) / 4;
  int cfblocks = (E + 2047) / 2048;

  // layer 1: h = xb @ W1 (+ cfa build in extra blocks); y1 = agg + b1 + xb; relu
  k_gemm<<<gb + cfblocks, 256, 0, stream>>>(xb, Wt1, htmp, N, gb, csr, dinv, cfa, E);
  k_agg<<<ab, 256, 0, stream>>>((const unsigned short*)htmp, csr, roff, dinv, cfa, b1,
                                xb, nullptr, fbuf, N, 1);
  // layer 2
  k_gemm<<<gb, 256, 0, stream>>>(fbuf, Wt2, htmp, N, gb, nullptr, nullptr, nullptr, 0);
  k_agg<<<ab, 256, 0, stream>>>((const unsigned short*)htmp, csr, roff, dinv, cfa, b2,
                                xb, nullptr, fbuf, N, 1);
  // layer 3 -> fp32 out
  k_gemm<<<gb, 256, 0, stream>>>(fbuf, Wt2, htmp, N, gb, nullptr, nullptr, nullptr, 0);
  k_agg<<<ab, 256, 0, stream>>>((const unsigned short*)htmp, csr, roff, dinv, cfa, b2,
                                xb, out, nullptr, N, 0);
}